// Round 3
// baseline (930.500 us; speedup 1.0000x reference)
//
#include <hip/hip_runtime.h>
#include <hip/hip_fp16.h>

#define NB 4
#define NR 256
#define NC 256
#define NCOIL 32
#define NSEG 4
#define NPOL 2
#define OD 276
#define OFF 10

typedef float2 c32;

__device__ __forceinline__ c32 cmul(c32 a, c32 b){
  return make_float2(a.x*b.x - a.y*b.y, a.x*b.y + a.y*b.x);
}
__device__ __forceinline__ c32 cmulj(c32 a, c32 b){ // a * conj(b)
  return make_float2(a.x*b.x + a.y*b.y, a.y*b.x - a.x*b.y);
}
// pad every 8 complex to break power-of-2 LDS bank strides
__device__ __forceinline__ int pd(int a){ return a + (a >> 3); }

__device__ __forceinline__ void wsync(){ __builtin_amdgcn_wave_barrier(); }

// tab[k] = exp(-2*pi*i*k/256)
__device__ __forceinline__ void init_tab(c32* tab, int tid){
  float th = (float)tid * 0.0245436926061703f; // 2*pi/256
  float sn, cs;
  sincosf(th, &sn, &cs);
  tab[tid] = make_float2(cs, -sn);
}

// 256-pt FFT, radix-4 Stockham, one wave (64 lanes), 4 complex per lane.
// WAVE-SYNCHRONOUS: b0/b1 must be private to the calling wave. A wave's LDS
// ops complete in order and lanes are lockstep, so no block barriers needed.
// xin[i] = x[u+64*i]; xout[t] = X[u+64*t]. DIR=+1 fwd, DIR=-1 unnorm inverse.
template<int DIR>
__device__ __forceinline__ void fft256(const c32* xin, c32* xout,
                                       c32* b0, c32* b1, const c32* tab, int u){
  c32* bufs[2] = { b0, b1 };
  #pragma unroll
  for (int s = 0; s < 4; ++s){
    const int m = 1 << (2*s);
    c32 a0, a1, a2, a3;
    if (s == 0){ a0 = xin[0]; a1 = xin[1]; a2 = xin[2]; a3 = xin[3]; }
    else {
      const c32* src = bufs[(s+1)&1];
      a0 = src[pd(u)]; a1 = src[pd(u+64)]; a2 = src[pd(u+128)]; a3 = src[pd(u+192)];
    }
    c32 s0 = make_float2(a0.x+a2.x, a0.y+a2.y);
    c32 d0 = make_float2(a0.x-a2.x, a0.y-a2.y);
    c32 s1 = make_float2(a1.x+a3.x, a1.y+a3.y);
    c32 d1 = make_float2(a1.x-a3.x, a1.y-a3.y);
    c32 X0 = make_float2(s0.x+s1.x, s0.y+s1.y);
    c32 X2 = make_float2(s0.x-s1.x, s0.y-s1.y);
    c32 X1, X3;
    if (DIR > 0){
      X1 = make_float2(d0.x + d1.y, d0.y - d1.x);  // d0 - i*d1
      X3 = make_float2(d0.x - d1.y, d0.y + d1.x);  // d0 + i*d1
    } else {
      X1 = make_float2(d0.x - d1.y, d0.y + d1.x);
      X3 = make_float2(d0.x + d1.y, d0.y - d1.x);
    }
    int e1 = u & ~(m-1);                 // twiddle exponent
    c32 w1 = tab[e1];
    c32 w2 = tab[(2*e1) & 255];
    c32 w3 = tab[(3*e1) & 255];
    if (DIR < 0){ w1.y = -w1.y; w2.y = -w2.y; w3.y = -w3.y; }
    X1 = cmul(X1, w1); X2 = cmul(X2, w2); X3 = cmul(X3, w3);
    if (s == 3){
      xout[0] = X0; xout[1] = X1; xout[2] = X2; xout[3] = X3;
    } else {
      c32* dst = bufs[s&1];
      int j = u >> (2*s);
      int k = u & (m-1);
      int base = k + 4*m*j;
      dst[pd(base)]      = X0;
      dst[pd(base+m)]    = X1;
      dst[pd(base+2*m)]  = X2;
      dst[pd(base+3*m)]  = X3;
    }
    wsync();
  }
}

// ---------------------------------------------------------------------------
__global__ __launch_bounds__(256) void zero_kernel(float* __restrict__ out, int n){
  int i = blockIdx.x*256 + threadIdx.x;
  if (i < n) out[i] = 0.0f;
}

// ---------------------------------------------------------------------------
// pack_common: for b in [b0, b0+nb):
// img_t[bl][pol][r][c] = crop(x)*(-1)^{r+c}/256 ; w_t[bl][pol*4+seg][r][c];
// m_t[bl][pol*4+seg][c][r].  grid: nb*NR blocks of 256 (thread = c)
__global__ __launch_bounds__(256) void pack_common_kernel(
    int b0,
    const float* __restrict__ x_re, const float* __restrict__ x_im,
    const float* __restrict__ wm_re, const float* __restrict__ wm_im,
    const float* __restrict__ mask,
    c32* __restrict__ img_t, c32* __restrict__ w_t, float* __restrict__ m_t)
{
  int r = blockIdx.x & (NR-1);
  int bl = blockIdx.x >> 8;
  int b = b0 + bl;
  int c = threadIdx.x;
  const size_t PL = (size_t)NR*NC;
  float sc = (((r + c) & 1) ? -1.0f : 1.0f) * (1.0f/256.0f);
  size_t xrow = (((size_t)b*OD) + (r+OFF))*OD + (c+OFF);
  #pragma unroll
  for (int pol = 0; pol < NPOL; ++pol){
    size_t xi = xrow*NPOL + pol;
    img_t[((size_t)(bl*NPOL+pol))*PL + (size_t)r*NC + c] =
        make_float2(x_re[xi]*sc, x_im[xi]*sc);
  }
  size_t wbase = (((size_t)b*NR + r)*NC + c)*(NPOL*NSEG);
  const float4* wre4 = (const float4*)&wm_re[wbase];
  const float4* wim4 = (const float4*)&wm_im[wbase];
  const float4* mk4  = (const float4*)&mask[wbase];
  #pragma unroll
  for (int pol = 0; pol < NPOL; ++pol){
    float4 re = wre4[pol], im = wim4[pol], mk = mk4[pol];
    float rr[4] = {re.x, re.y, re.z, re.w};
    float ii[4] = {im.x, im.y, im.z, im.w};
    float mm[4] = {mk.x, mk.y, mk.z, mk.w};
    #pragma unroll
    for (int seg = 0; seg < NSEG; ++seg){
      int ps = bl*(NPOL*NSEG) + pol*NSEG + seg;
      w_t[(size_t)ps*PL + (size_t)r*NC + c] = make_float2(rr[seg], ii[seg]);
      m_t[(size_t)ps*PL + (size_t)c*NR + r] = mm[seg];
    }
  }
}

// pack_csm: for b in [b0,b0+nb), coils [c0,c0+CH): c_t[bl*CH+cl][r][c]
// grid: nb*NR blocks of 256
__global__ __launch_bounds__(256) void pack_csm_kernel(
    int b0, int c0, int CH,
    const float* __restrict__ csm_re, const float* __restrict__ csm_im,
    c32* __restrict__ c_t)
{
  int r = blockIdx.x & (NR-1);
  int bl = blockIdx.x >> 8;
  int b = b0 + bl;
  int c = threadIdx.x;
  const size_t PL = (size_t)NR*NC;
  size_t base = (((size_t)b*NR + r)*NC + c)*NCOIL + c0;
  c32* cp = c_t + (size_t)bl*CH*PL + (size_t)r*NC + c;
  for (int cl = 0; cl < CH; cl += 4){
    float4 re = *(const float4*)&csm_re[base + cl];
    float4 im = *(const float4*)&csm_im[base + cl];
    cp[(size_t)(cl+0)*PL] = make_float2(re.x, im.x);
    cp[(size_t)(cl+1)*PL] = make_float2(re.y, im.y);
    cp[(size_t)(cl+2)*PL] = make_float2(re.z, im.z);
    cp[(size_t)(cl+3)*PL] = make_float2(re.w, im.w);
  }
}

// ---------------------------------------------------------------------------
// stage A: g = img*w*csm (scaled/signed already), row-FFT, write T1[p][c][r] fp16
// grid: CH*NPOL*NSEG*16 blocks of 256 (4 waves, 4 rows each)
__global__ __launch_bounds__(256) void stageA_kernel(
    const c32* __restrict__ img_t, const c32* __restrict__ w_t,
    const c32* __restrict__ c_t, __half2* __restrict__ T1)
{
  __shared__ c32 tab[256];
  __shared__ c32 fbuf[4][2][288];
  __shared__ __half2 tile[NC*17];
  int tid = threadIdx.x;
  int u = tid & 63, w = tid >> 6;
  init_tab(tab, tid);
  __syncthreads();
  int bid = blockIdx.x;
  int p  = bid >> 4;           // ((cl*NPOL)+pol)*NSEG+seg
  int rt = bid & 15;
  int seg = p & 3, pol = (p>>2) & 1, cl = p >> 3;

  for (int ri = 0; ri < 4; ++ri){
    int rl = w*4 + ri;
    int r = rt*16 + rl;
    const c32* ir = img_t + ((size_t)pol*NR + r)*NC;
    const c32* wr = w_t  + ((size_t)(pol*NSEG+seg)*NR + r)*NC;
    const c32* cr = c_t  + ((size_t)cl*NR + r)*NC;
    c32 xin[4], xout[4];
    #pragma unroll
    for (int i = 0; i < 4; ++i){
      int c = u + 64*i;
      xin[i] = cmul(cmul(ir[c], wr[c]), cr[c]);
    }
    fft256<1>(xin, xout, fbuf[w][0], fbuf[w][1], tab, u);
    #pragma unroll
    for (int t = 0; t < 4; ++t){
      int c = u + 64*t;
      tile[c*17 + rl] = __floats2half2_rn(xout[t].x, xout[t].y);
    }
  }
  __syncthreads();
  __half2* tp = T1 + (size_t)p*(NR*NC);
  int r0 = rt*16;
  #pragma unroll
  for (int cb = 0; cb < 16; ++cb){
    int cc = w*64 + cb*4 + (u >> 4);
    int rl = u & 15;
    tp[cc*NR + r0 + rl] = tile[cc*17 + rl];
  }
}

// ---------------------------------------------------------------------------
// stage B (in-place on T1): per column c: col-FFT per seg, K = sum(mask*X);
// then per seg': H = K*mask, col-iFFT, *(1/256), store back.
// grid: CH*NPOL*64 blocks of 256 (4 waves = 4 columns)
__global__ __launch_bounds__(256) void stageB_kernel(
    __half2* __restrict__ T1, const float* __restrict__ m_t)
{
  __shared__ c32 tab[256];
  __shared__ c32 fbuf[4][2][288];
  int tid = threadIdx.x;
  int u = tid & 63, w = tid >> 6;
  init_tab(tab, tid);
  __syncthreads();
  int bid = blockIdx.x;
  int g = bid >> 6;            // cl*NPOL+pol
  int ctile = bid & 63;
  int c = ctile*4 + w;
  int pol = g & 1;
  c32 K[4];
  #pragma unroll
  for (int t = 0; t < 4; ++t) K[t] = make_float2(0.f, 0.f);

  #pragma unroll 1
  for (int seg = 0; seg < NSEG; ++seg){
    const __half2* tp = T1 + ((size_t)(g*NSEG+seg))*(NR*NC) + (size_t)c*NR;
    const float* mp = m_t + ((size_t)(pol*NSEG+seg)*NC + c)*NR;
    c32 xin[4], xout[4];
    float mv[4];
    #pragma unroll
    for (int i = 0; i < 4; ++i){
      xin[i] = __half22float2(tp[u + 64*i]);
      mv[i]  = mp[u + 64*i];
    }
    fft256<1>(xin, xout, fbuf[w][0], fbuf[w][1], tab, u);
    #pragma unroll
    for (int t = 0; t < 4; ++t){
      K[t].x += mv[t]*xout[t].x;
      K[t].y += mv[t]*xout[t].y;
    }
  }
  #pragma unroll 1
  for (int seg = 0; seg < NSEG; ++seg){
    const float* mp = m_t + ((size_t)(pol*NSEG+seg)*NC + c)*NR;
    c32 xin[4], xout[4];
    #pragma unroll
    for (int t = 0; t < 4; ++t){
      float mv = mp[u + 64*t];
      xin[t] = make_float2(K[t].x*mv, K[t].y*mv);
    }
    fft256<-1>(xin, xout, fbuf[w][0], fbuf[w][1], tab, u);
    __half2* tp = T1 + ((size_t)(g*NSEG+seg))*(NR*NC) + (size_t)c*NR;
    #pragma unroll
    for (int t = 0; t < 4; ++t){
      tp[u + 64*t] = __floats2half2_rn(xout[t].x*(1.0f/256.0f),
                                       xout[t].y*(1.0f/256.0f));
    }
  }
}

// ---------------------------------------------------------------------------
// stage C: row-iFFT, * conj(w)*conj(csm), accumulate over 4 segs of ONE coil,
// sign (-1)^{r+c}, atomicAdd into zeroed out.
// grid: CH*NPOL*16 blocks of 256 (4 waves)
__global__ __launch_bounds__(256) void stageC_kernel(
    int b, const __half2* __restrict__ T1, const c32* __restrict__ w_t,
    const c32* __restrict__ c_t, float* __restrict__ out)
{
  __shared__ c32 tab[256];
  __shared__ c32 fbuf[4][2][288];
  __shared__ __half2 tile[NC*17];
  int tid = threadIdx.x, u = tid & 63, w = tid >> 6;
  init_tab(tab, tid);
  __syncthreads();
  int bid = blockIdx.x;
  int rt = bid & 15, pol = (bid>>4) & 1, cl = bid >> 5;
  c32 acc[4][4];
  #pragma unroll
  for (int a = 0; a < 4; ++a)
    #pragma unroll
    for (int t = 0; t < 4; ++t) acc[a][t] = make_float2(0.f, 0.f);

  #pragma unroll 1
  for (int seg = 0; seg < NSEG; ++seg){
    int p = (cl*NPOL+pol)*NSEG + seg;
    const __half2* tp = T1 + (size_t)p*(NR*NC) + (size_t)tid*NR + rt*16;
    // vector-load 16 half2 (64B, aligned), scatter into padded tile
    float4 v[4];
    const float4* tpv = (const float4*)tp;
    #pragma unroll
    for (int k = 0; k < 4; ++k) v[k] = tpv[k];
    const __half2* hv = (const __half2*)v;
    #pragma unroll
    for (int j = 0; j < 16; ++j) tile[tid*17 + j] = hv[j];
    __syncthreads();
    #pragma unroll
    for (int ri = 0; ri < 4; ++ri){
      int rl = w + 4*ri;
      int r = rt*16 + rl;
      c32 xin[4], xout[4];
      #pragma unroll
      for (int i = 0; i < 4; ++i)
        xin[i] = __half22float2(tile[(u + 64*i)*17 + rl]);
      fft256<-1>(xin, xout, fbuf[w][0], fbuf[w][1], tab, u);
      const c32* wr = w_t + ((size_t)(pol*NSEG+seg)*NR + r)*NC;
      const c32* cr = c_t + ((size_t)cl*NR + r)*NC;
      #pragma unroll
      for (int t = 0; t < 4; ++t){
        int cp = u + 64*t;
        c32 vv = cmulj(xout[t], wr[cp]);
        vv = cmulj(vv, cr[cp]);
        acc[ri][t].x += vv.x;
        acc[ri][t].y += vv.y;
      }
    }
    __syncthreads();
  }
  #pragma unroll
  for (int ri = 0; ri < 4; ++ri){
    int rl = w + 4*ri;
    int r = rt*16 + rl;
    #pragma unroll
    for (int t = 0; t < 4; ++t){
      int cp = u + 64*t;
      float sgn = ((r + cp) & 1) ? -1.0f : 1.0f;
      size_t o = ((((size_t)b*OD + (r+OFF))*OD + (cp+OFF))*NPOL + pol)*2;
      atomicAdd(&out[o],   sgn*acc[ri][t].x);
      atomicAdd(&out[o+1], sgn*acc[ri][t].y);
    }
  }
}

// ---------------------------------------------------------------------------
extern "C" void kernel_launch(void* const* d_in, const int* in_sizes, int n_in,
                              void* d_out, int out_size, void* d_ws, size_t ws_size,
                              hipStream_t stream)
{
  (void)in_sizes; (void)n_in;
  const float* x_re   = (const float*)d_in[0];
  const float* x_im   = (const float*)d_in[1];
  const float* csm_re = (const float*)d_in[2];
  const float* csm_im = (const float*)d_in[3];
  const float* wm_re  = (const float*)d_in[4];
  const float* wm_im  = (const float*)d_in[5];
  const float* mask   = (const float*)d_in[6];

  const size_t PL = (size_t)NR*NC;
  const size_t imgB1 = (size_t)NPOL*PL*sizeof(c32);           // 1 MiB / batch
  const size_t wB1   = (size_t)NPOL*NSEG*PL*sizeof(c32);      // 4 MiB / batch
  const size_t mB1   = (size_t)NPOL*NSEG*PL*sizeof(float);    // 2 MiB / batch
  const size_t csmB1 = (size_t)NCOIL*PL*sizeof(c32);          // 16 MiB / batch
  const size_t T1B   = (size_t)NCOIL*NPOL*NSEG*PL*4;          // 67 MiB (one batch)

  float* out = (float*)d_out;
  zero_kernel<<<(out_size + 255)/256, 256, 0, stream>>>(out, out_size);

  char* ws = (char*)d_ws;
  size_t tierA_need = NB*(imgB1 + wB1 + mB1) + NB*csmB1 + T1B;  // ~159 MiB

  if (ws_size >= tierA_need){
    // ---- tier A: pack everything once, loop batches over the big stages ----
    c32* img_t = (c32*)ws;
    c32* w_t   = (c32*)(ws + NB*imgB1);
    float* m_t = (float*)(ws + NB*(imgB1 + wB1));
    c32* c_t   = (c32*)(ws + NB*(imgB1 + wB1 + mB1));
    __half2* T1 = (__half2*)(ws + NB*(imgB1 + wB1 + mB1) + NB*csmB1);

    pack_common_kernel<<<NB*NR, 256, 0, stream>>>(0, x_re, x_im, wm_re, wm_im,
                                                  mask, img_t, w_t, m_t);
    pack_csm_kernel<<<NB*NR, 256, 0, stream>>>(0, 0, NCOIL, csm_re, csm_im, c_t);
    for (int b = 0; b < NB; ++b){
      c32* img_b = img_t + (size_t)b*NPOL*PL;
      c32* w_b   = w_t   + (size_t)b*NPOL*NSEG*PL;
      float* m_b = m_t   + (size_t)b*NPOL*NSEG*PL;
      c32* c_b   = c_t   + (size_t)b*NCOIL*PL;
      stageA_kernel<<<NCOIL*NPOL*NSEG*16, 256, 0, stream>>>(img_b, w_b, c_b, T1);
      stageB_kernel<<<NCOIL*NPOL*64, 256, 0, stream>>>(T1, m_b);
      stageC_kernel<<<NCOIL*NPOL*16, 256, 0, stream>>>(b, T1, w_b, c_b, out);
    }
  } else {
    // ---- tier B/C: per-batch packing, coil-chunked (round-2 layout) ----
    const size_t common = imgB1 + wB1 + mB1;
    int CH = 32;
    while (CH > 2){
      size_t need = common + (size_t)CH*(PL*sizeof(c32) + (size_t)NPOL*NSEG*PL*4);
      if (need <= ws_size) break;
      CH >>= 1;
    }
    c32* img_t = (c32*)ws;
    c32* w_t   = (c32*)(ws + imgB1);
    float* m_t = (float*)(ws + imgB1 + wB1);
    c32* c_t   = (c32*)(ws + common);
    __half2* T1 = (__half2*)(ws + common + (size_t)CH*PL*sizeof(c32));

    for (int b = 0; b < NB; ++b){
      pack_common_kernel<<<NR, 256, 0, stream>>>(b, x_re, x_im, wm_re, wm_im,
                                                 mask, img_t, w_t, m_t);
      for (int c0 = 0; c0 < NCOIL; c0 += CH){
        pack_csm_kernel<<<NR, 256, 0, stream>>>(b, c0, CH, csm_re, csm_im, c_t);
        stageA_kernel<<<CH*NPOL*NSEG*16, 256, 0, stream>>>(img_t, w_t, c_t, T1);
        stageB_kernel<<<CH*NPOL*64, 256, 0, stream>>>(T1, m_t);
        stageC_kernel<<<CH*NPOL*16, 256, 0, stream>>>(b, T1, w_t, c_t, out);
      }
    }
  }
}

// Round 4
// 574.795 us; speedup vs baseline: 1.6188x; 1.6188x over previous
//
#include <hip/hip_runtime.h>
#include <hip/hip_fp16.h>

#define NB 4
#define NR 256
#define NC 256
#define NCOIL 32
#define NSEG 4
#define NPOL 2
#define OD 276
#define OFF 10
#define NCC 16          // partial chunks = NCOIL/2 (2 coils per stageC block)

typedef float2 c32;

__device__ __forceinline__ c32 cmul(c32 a, c32 b){
  return make_float2(a.x*b.x - a.y*b.y, a.x*b.y + a.y*b.x);
}
__device__ __forceinline__ c32 cmulj(c32 a, c32 b){ // a * conj(b)
  return make_float2(a.x*b.x + a.y*b.y, a.y*b.x - a.x*b.y);
}
// pad every 8 complex to break power-of-2 LDS bank strides
__device__ __forceinline__ int pd(int a){ return a + (a >> 3); }

__device__ __forceinline__ void wsync(){ __builtin_amdgcn_wave_barrier(); }

// tab[k] = exp(-2*pi*i*k/256)
__device__ __forceinline__ void init_tab(c32* tab, int tid){
  float th = (float)tid * 0.0245436926061703f; // 2*pi/256
  float sn, cs;
  sincosf(th, &sn, &cs);
  tab[tid] = make_float2(cs, -sn);
}

// 256-pt FFT, radix-4 Stockham, one wave (64 lanes), 4 complex per lane.
// WAVE-SYNCHRONOUS: b0/b1 must be private to the calling wave.
// xin[i] = x[u+64*i]; xout[t] = X[u+64*t]. DIR=+1 fwd, DIR=-1 unnorm inverse.
template<int DIR>
__device__ __forceinline__ void fft256(const c32* xin, c32* xout,
                                       c32* b0, c32* b1, const c32* tab, int u){
  c32* bufs[2] = { b0, b1 };
  #pragma unroll
  for (int s = 0; s < 4; ++s){
    const int m = 1 << (2*s);
    c32 a0, a1, a2, a3;
    if (s == 0){ a0 = xin[0]; a1 = xin[1]; a2 = xin[2]; a3 = xin[3]; }
    else {
      const c32* src = bufs[(s+1)&1];
      a0 = src[pd(u)]; a1 = src[pd(u+64)]; a2 = src[pd(u+128)]; a3 = src[pd(u+192)];
    }
    c32 s0 = make_float2(a0.x+a2.x, a0.y+a2.y);
    c32 d0 = make_float2(a0.x-a2.x, a0.y-a2.y);
    c32 s1 = make_float2(a1.x+a3.x, a1.y+a3.y);
    c32 d1 = make_float2(a1.x-a3.x, a1.y-a3.y);
    c32 X0 = make_float2(s0.x+s1.x, s0.y+s1.y);
    c32 X2 = make_float2(s0.x-s1.x, s0.y-s1.y);
    c32 X1, X3;
    if (DIR > 0){
      X1 = make_float2(d0.x + d1.y, d0.y - d1.x);  // d0 - i*d1
      X3 = make_float2(d0.x - d1.y, d0.y + d1.x);  // d0 + i*d1
    } else {
      X1 = make_float2(d0.x - d1.y, d0.y + d1.x);
      X3 = make_float2(d0.x + d1.y, d0.y - d1.x);
    }
    int e1 = u & ~(m-1);                 // twiddle exponent
    c32 w1 = tab[e1];
    c32 w2 = tab[(2*e1) & 255];
    c32 w3 = tab[(3*e1) & 255];
    if (DIR < 0){ w1.y = -w1.y; w2.y = -w2.y; w3.y = -w3.y; }
    X1 = cmul(X1, w1); X2 = cmul(X2, w2); X3 = cmul(X3, w3);
    if (s == 3){
      xout[0] = X0; xout[1] = X1; xout[2] = X2; xout[3] = X3;
    } else {
      c32* dst = bufs[s&1];
      int j = u >> (2*s);
      int k = u & (m-1);
      int base = k + 4*m*j;
      dst[pd(base)]      = X0;
      dst[pd(base+m)]    = X1;
      dst[pd(base+2*m)]  = X2;
      dst[pd(base+3*m)]  = X3;
    }
    wsync();
  }
}

// ---------------------------------------------------------------------------
__global__ __launch_bounds__(256) void zero_kernel(float* __restrict__ out, int n){
  int i = blockIdx.x*256 + threadIdx.x;
  if (i < n) out[i] = 0.0f;
}

// ---------------------------------------------------------------------------
// pack_common: for b in [b0, b0+nb):
// img_t[bl][pol][r][c] = crop(x)*(-1)^{r+c}/256 ; w_t[bl][pol*4+seg][r][c];
// m_t[bl][pol*4+seg][c][r].  grid: nb*NR blocks of 256 (thread = c)
__global__ __launch_bounds__(256) void pack_common_kernel(
    int b0,
    const float* __restrict__ x_re, const float* __restrict__ x_im,
    const float* __restrict__ wm_re, const float* __restrict__ wm_im,
    const float* __restrict__ mask,
    c32* __restrict__ img_t, c32* __restrict__ w_t, float* __restrict__ m_t)
{
  int r = blockIdx.x & (NR-1);
  int bl = blockIdx.x >> 8;
  int b = b0 + bl;
  int c = threadIdx.x;
  const size_t PL = (size_t)NR*NC;
  float sc = (((r + c) & 1) ? -1.0f : 1.0f) * (1.0f/256.0f);
  size_t xrow = (((size_t)b*OD) + (r+OFF))*OD + (c+OFF);
  #pragma unroll
  for (int pol = 0; pol < NPOL; ++pol){
    size_t xi = xrow*NPOL + pol;
    img_t[((size_t)(bl*NPOL+pol))*PL + (size_t)r*NC + c] =
        make_float2(x_re[xi]*sc, x_im[xi]*sc);
  }
  size_t wbase = (((size_t)b*NR + r)*NC + c)*(NPOL*NSEG);
  const float4* wre4 = (const float4*)&wm_re[wbase];
  const float4* wim4 = (const float4*)&wm_im[wbase];
  const float4* mk4  = (const float4*)&mask[wbase];
  #pragma unroll
  for (int pol = 0; pol < NPOL; ++pol){
    float4 re = wre4[pol], im = wim4[pol], mk = mk4[pol];
    float rr[4] = {re.x, re.y, re.z, re.w};
    float ii[4] = {im.x, im.y, im.z, im.w};
    float mm[4] = {mk.x, mk.y, mk.z, mk.w};
    #pragma unroll
    for (int seg = 0; seg < NSEG; ++seg){
      int ps = bl*(NPOL*NSEG) + pol*NSEG + seg;
      w_t[(size_t)ps*PL + (size_t)r*NC + c] = make_float2(rr[seg], ii[seg]);
      m_t[(size_t)ps*PL + (size_t)c*NR + r] = mm[seg];
    }
  }
}

// pack_csm: for b in [b0,b0+nb), coils [c0,c0+CH): c_t[bl*CH+cl][r][c]
// grid: nb*NR blocks of 256
__global__ __launch_bounds__(256) void pack_csm_kernel(
    int b0, int c0, int CH,
    const float* __restrict__ csm_re, const float* __restrict__ csm_im,
    c32* __restrict__ c_t)
{
  int r = blockIdx.x & (NR-1);
  int bl = blockIdx.x >> 8;
  int b = b0 + bl;
  int c = threadIdx.x;
  const size_t PL = (size_t)NR*NC;
  size_t base = (((size_t)b*NR + r)*NC + c)*NCOIL + c0;
  c32* cp = c_t + (size_t)bl*CH*PL + (size_t)r*NC + c;
  for (int cl = 0; cl < CH; cl += 4){
    float4 re = *(const float4*)&csm_re[base + cl];
    float4 im = *(const float4*)&csm_im[base + cl];
    cp[(size_t)(cl+0)*PL] = make_float2(re.x, im.x);
    cp[(size_t)(cl+1)*PL] = make_float2(re.y, im.y);
    cp[(size_t)(cl+2)*PL] = make_float2(re.z, im.z);
    cp[(size_t)(cl+3)*PL] = make_float2(re.w, im.w);
  }
}

// ---------------------------------------------------------------------------
// stage A: g = img*w*csm (scaled/signed already), row-FFT, write T1[p][c][r] fp16
// grid: CH*NPOL*NSEG*16 blocks of 256 (4 waves, 4 rows each)
__global__ __launch_bounds__(256) void stageA_kernel(
    const c32* __restrict__ img_t, const c32* __restrict__ w_t,
    const c32* __restrict__ c_t, __half2* __restrict__ T1)
{
  __shared__ c32 tab[256];
  __shared__ c32 fbuf[4][2][288];
  __shared__ __half2 tile[NC*17];
  int tid = threadIdx.x;
  int u = tid & 63, w = tid >> 6;
  init_tab(tab, tid);
  __syncthreads();
  int bid = blockIdx.x;
  int p  = bid >> 4;           // ((cl*NPOL)+pol)*NSEG+seg
  int rt = bid & 15;
  int seg = p & 3, pol = (p>>2) & 1, cl = p >> 3;

  for (int ri = 0; ri < 4; ++ri){
    int rl = w*4 + ri;
    int r = rt*16 + rl;
    const c32* ir = img_t + ((size_t)pol*NR + r)*NC;
    const c32* wr = w_t  + ((size_t)(pol*NSEG+seg)*NR + r)*NC;
    const c32* cr = c_t  + ((size_t)cl*NR + r)*NC;
    c32 xin[4], xout[4];
    #pragma unroll
    for (int i = 0; i < 4; ++i){
      int c = u + 64*i;
      xin[i] = cmul(cmul(ir[c], wr[c]), cr[c]);
    }
    fft256<1>(xin, xout, fbuf[w][0], fbuf[w][1], tab, u);
    #pragma unroll
    for (int t = 0; t < 4; ++t){
      int c = u + 64*t;
      tile[c*17 + rl] = __floats2half2_rn(xout[t].x, xout[t].y);
    }
  }
  __syncthreads();
  __half2* tp = T1 + (size_t)p*(NR*NC);
  int r0 = rt*16;
  #pragma unroll
  for (int cb = 0; cb < 16; ++cb){
    int cc = w*64 + cb*4 + (u >> 4);
    int rl = u & 15;
    tp[cc*NR + r0 + rl] = tile[cc*17 + rl];
  }
}

// ---------------------------------------------------------------------------
// stage B (in-place on T1): per column c: col-FFT per seg, K = sum(mask*X);
// then per seg': H = K*mask, col-iFFT, *(1/256), store back.
// grid: CH*NPOL*64 blocks of 256 (4 waves = 4 columns)
__global__ __launch_bounds__(256) void stageB_kernel(
    __half2* __restrict__ T1, const float* __restrict__ m_t)
{
  __shared__ c32 tab[256];
  __shared__ c32 fbuf[4][2][288];
  int tid = threadIdx.x;
  int u = tid & 63, w = tid >> 6;
  init_tab(tab, tid);
  __syncthreads();
  int bid = blockIdx.x;
  int g = bid >> 6;            // cl*NPOL+pol
  int ctile = bid & 63;
  int c = ctile*4 + w;
  int pol = g & 1;
  c32 K[4];
  #pragma unroll
  for (int t = 0; t < 4; ++t) K[t] = make_float2(0.f, 0.f);

  #pragma unroll 1
  for (int seg = 0; seg < NSEG; ++seg){
    const __half2* tp = T1 + ((size_t)(g*NSEG+seg))*(NR*NC) + (size_t)c*NR;
    const float* mp = m_t + ((size_t)(pol*NSEG+seg)*NC + c)*NR;
    c32 xin[4], xout[4];
    float mv[4];
    #pragma unroll
    for (int i = 0; i < 4; ++i){
      xin[i] = __half22float2(tp[u + 64*i]);
      mv[i]  = mp[u + 64*i];
    }
    fft256<1>(xin, xout, fbuf[w][0], fbuf[w][1], tab, u);
    #pragma unroll
    for (int t = 0; t < 4; ++t){
      K[t].x += mv[t]*xout[t].x;
      K[t].y += mv[t]*xout[t].y;
    }
  }
  #pragma unroll 1
  for (int seg = 0; seg < NSEG; ++seg){
    const float* mp = m_t + ((size_t)(pol*NSEG+seg)*NC + c)*NR;
    c32 xin[4], xout[4];
    #pragma unroll
    for (int t = 0; t < 4; ++t){
      float mv = mp[u + 64*t];
      xin[t] = make_float2(K[t].x*mv, K[t].y*mv);
    }
    fft256<-1>(xin, xout, fbuf[w][0], fbuf[w][1], tab, u);
    __half2* tp = T1 + ((size_t)(g*NSEG+seg))*(NR*NC) + (size_t)c*NR;
    #pragma unroll
    for (int t = 0; t < 4; ++t){
      tp[u + 64*t] = __floats2half2_rn(xout[t].x*(1.0f/256.0f),
                                       xout[t].y*(1.0f/256.0f));
    }
  }
}

// ---------------------------------------------------------------------------
// stage C (partial): row-iFFT, * conj(w)*conj(csm), accumulate 2 coils x 4 segs,
// write fp16 partial[ch][pol][r][c].  NO atomics.  One-plane-ahead prefetch.
// grid: NCC*NPOL*16 = 512 blocks of 256 (4 waves)
__global__ __launch_bounds__(256) void stageC_part_kernel(
    const __half2* __restrict__ T1, const c32* __restrict__ w_t,
    const c32* __restrict__ c_t, __half2* __restrict__ part)
{
  __shared__ c32 tab[256];
  __shared__ c32 fbuf[4][2][288];
  __shared__ __half2 tile[NC*17];
  int tid = threadIdx.x, u = tid & 63, w = tid >> 6;
  init_tab(tab, tid);
  __syncthreads();
  int bid = blockIdx.x;
  int rt = bid & 15, pol = (bid>>4) & 1, ch = bid >> 5;   // ch in [0,16)
  const size_t PL = (size_t)NR*NC;
  c32 acc[4][4];
  #pragma unroll
  for (int a = 0; a < 4; ++a)
    #pragma unroll
    for (int t = 0; t < 4; ++t) acc[a][t] = make_float2(0.f, 0.f);

  // prologue: load plane 0 tile chunk (16 half2 = 64B per thread)
  float4 v[4];
  {
    int p0 = ((ch*2+0)*NPOL+pol)*NSEG + 0;
    const float4* tpv = (const float4*)(T1 + (size_t)p0*PL + (size_t)tid*NR + rt*16);
    #pragma unroll
    for (int k = 0; k < 4; ++k) v[k] = tpv[k];
  }

  #pragma unroll 1
  for (int pl = 0; pl < 2*NSEG; ++pl){
    int ci = pl >> 2, seg = pl & 3;
    int cl = ch*2 + ci;
    // scatter current plane into padded tile
    const __half2* hv = (const __half2*)v;
    #pragma unroll
    for (int j = 0; j < 16; ++j) tile[tid*17 + j] = hv[j];
    __syncthreads();
    // prefetch next plane while computing this one
    if (pl < 2*NSEG-1){
      int ci2 = (pl+1) >> 2, seg2 = (pl+1) & 3;
      int p2 = ((ch*2+ci2)*NPOL+pol)*NSEG + seg2;
      const float4* tpv = (const float4*)(T1 + (size_t)p2*PL + (size_t)tid*NR + rt*16);
      #pragma unroll
      for (int k = 0; k < 4; ++k) v[k] = tpv[k];
    }
    #pragma unroll
    for (int ri = 0; ri < 4; ++ri){
      int rl = w + 4*ri;
      int r = rt*16 + rl;
      c32 xin[4], xout[4];
      #pragma unroll
      for (int i = 0; i < 4; ++i)
        xin[i] = __half22float2(tile[(u + 64*i)*17 + rl]);
      fft256<-1>(xin, xout, fbuf[w][0], fbuf[w][1], tab, u);
      const c32* wr = w_t + ((size_t)(pol*NSEG+seg)*NR + r)*NC;
      const c32* cr = c_t + ((size_t)cl*NR + r)*NC;
      #pragma unroll
      for (int t = 0; t < 4; ++t){
        int cp = u + 64*t;
        c32 vv = cmulj(xout[t], wr[cp]);
        vv = cmulj(vv, cr[cp]);
        acc[ri][t].x += vv.x;
        acc[ri][t].y += vv.y;
      }
    }
    __syncthreads();
  }
  // coalesced fp16 partial store: part[(ch*NPOL+pol)][r][c]
  __half2* pp = part + ((size_t)(ch*NPOL+pol))*PL;
  #pragma unroll
  for (int ri = 0; ri < 4; ++ri){
    int r = rt*16 + w + 4*ri;
    #pragma unroll
    for (int t = 0; t < 4; ++t){
      int cp = u + 64*t;
      pp[(size_t)r*NC + cp] = __floats2half2_rn(acc[ri][t].x, acc[ri][t].y);
    }
  }
}

// reduceC: out interior = sign * sum over 16 chunks of partial. Plain stores.
// grid: NR blocks of 256 (thread = c, block = r)
__global__ __launch_bounds__(256) void reduceC_kernel(
    int b, const __half2* __restrict__ part, float* __restrict__ out)
{
  int r = blockIdx.x, c = threadIdx.x;
  const size_t PL = (size_t)NR*NC;
  float2 s[NPOL];
  #pragma unroll
  for (int pol = 0; pol < NPOL; ++pol) s[pol] = make_float2(0.f, 0.f);
  #pragma unroll 4
  for (int ch = 0; ch < NCC; ++ch){
    #pragma unroll
    for (int pol = 0; pol < NPOL; ++pol){
      float2 f = __half22float2(part[((size_t)(ch*NPOL+pol))*PL + (size_t)r*NC + c]);
      s[pol].x += f.x; s[pol].y += f.y;
    }
  }
  float sgn = ((r + c) & 1) ? -1.0f : 1.0f;
  float4 o = make_float4(sgn*s[0].x, sgn*s[0].y, sgn*s[1].x, sgn*s[1].y);
  size_t oidx = (((size_t)b*OD + (r+OFF))*OD + (c+OFF));   // float4 units
  ((float4*)out)[oidx] = o;
}

// ---------------------------------------------------------------------------
// fallback stage C with atomics (2 coils/block) for small workspaces
__global__ __launch_bounds__(256) void stageC_atomic_kernel(
    int b, const __half2* __restrict__ T1, const c32* __restrict__ w_t,
    const c32* __restrict__ c_t, float* __restrict__ out)
{
  __shared__ c32 tab[256];
  __shared__ c32 fbuf[4][2][288];
  __shared__ __half2 tile[NC*17];
  int tid = threadIdx.x, u = tid & 63, w = tid >> 6;
  init_tab(tab, tid);
  __syncthreads();
  int bid = blockIdx.x;
  int rt = bid & 15, pol = (bid>>4) & 1, cch = bid >> 5;
  c32 acc[4][4];
  #pragma unroll
  for (int a = 0; a < 4; ++a)
    #pragma unroll
    for (int t = 0; t < 4; ++t) acc[a][t] = make_float2(0.f, 0.f);

  #pragma unroll 1
  for (int ci = 0; ci < 2; ++ci){
    int cl = cch*2 + ci;
    #pragma unroll 1
    for (int seg = 0; seg < NSEG; ++seg){
      int p = (cl*NPOL+pol)*NSEG + seg;
      const __half2* tp = T1 + (size_t)p*(NR*NC) + (size_t)tid*NR + rt*16;
      float4 v[4];
      const float4* tpv = (const float4*)tp;
      #pragma unroll
      for (int k = 0; k < 4; ++k) v[k] = tpv[k];
      const __half2* hv = (const __half2*)v;
      #pragma unroll
      for (int j = 0; j < 16; ++j) tile[tid*17 + j] = hv[j];
      __syncthreads();
      #pragma unroll
      for (int ri = 0; ri < 4; ++ri){
        int rl = w + 4*ri;
        int r = rt*16 + rl;
        c32 xin[4], xout[4];
        #pragma unroll
        for (int i = 0; i < 4; ++i)
          xin[i] = __half22float2(tile[(u + 64*i)*17 + rl]);
        fft256<-1>(xin, xout, fbuf[w][0], fbuf[w][1], tab, u);
        const c32* wr = w_t + ((size_t)(pol*NSEG+seg)*NR + r)*NC;
        const c32* cr = c_t + ((size_t)cl*NR + r)*NC;
        #pragma unroll
        for (int t = 0; t < 4; ++t){
          int cp = u + 64*t;
          c32 vv = cmulj(xout[t], wr[cp]);
          vv = cmulj(vv, cr[cp]);
          acc[ri][t].x += vv.x;
          acc[ri][t].y += vv.y;
        }
      }
      __syncthreads();
    }
  }
  #pragma unroll
  for (int ri = 0; ri < 4; ++ri){
    int r = rt*16 + w + 4*ri;
    #pragma unroll
    for (int t = 0; t < 4; ++t){
      int cp = u + 64*t;
      float sgn = ((r + cp) & 1) ? -1.0f : 1.0f;
      size_t o = ((((size_t)b*OD + (r+OFF))*OD + (cp+OFF))*NPOL + pol)*2;
      atomicAdd(&out[o],   sgn*acc[ri][t].x);
      atomicAdd(&out[o+1], sgn*acc[ri][t].y);
    }
  }
}

// ---------------------------------------------------------------------------
extern "C" void kernel_launch(void* const* d_in, const int* in_sizes, int n_in,
                              void* d_out, int out_size, void* d_ws, size_t ws_size,
                              hipStream_t stream)
{
  (void)in_sizes; (void)n_in;
  const float* x_re   = (const float*)d_in[0];
  const float* x_im   = (const float*)d_in[1];
  const float* csm_re = (const float*)d_in[2];
  const float* csm_im = (const float*)d_in[3];
  const float* wm_re  = (const float*)d_in[4];
  const float* wm_im  = (const float*)d_in[5];
  const float* mask   = (const float*)d_in[6];

  const size_t PL = (size_t)NR*NC;
  const size_t imgB1 = (size_t)NPOL*PL*sizeof(c32);           // 1 MiB / batch
  const size_t wB1   = (size_t)NPOL*NSEG*PL*sizeof(c32);      // 4 MiB / batch
  const size_t mB1   = (size_t)NPOL*NSEG*PL*sizeof(float);    // 2 MiB / batch
  const size_t csmB1 = (size_t)NCOIL*PL*sizeof(c32);          // 16 MiB / batch
  const size_t T1B   = (size_t)NCOIL*NPOL*NSEG*PL*4;          // 64 MiB
  const size_t partB = (size_t)NCC*NPOL*PL*4;                 // 32 MiB fp16

  float* out = (float*)d_out;
  zero_kernel<<<(out_size + 255)/256, 256, 0, stream>>>(out, out_size);

  char* ws = (char*)d_ws;
  size_t mainNeed = NB*(imgB1 + wB1 + mB1) + csmB1 + T1B + partB;  // ~140 MiB

  if (ws_size >= mainNeed){
    // ---- main path: pack img/w/m once, per-batch csm + stages, no atomics ----
    c32* img_t = (c32*)ws;
    c32* w_t   = (c32*)(ws + NB*imgB1);
    float* m_t = (float*)(ws + NB*(imgB1 + wB1));
    c32* c_t   = (c32*)(ws + NB*(imgB1 + wB1 + mB1));
    __half2* T1 = (__half2*)(ws + NB*(imgB1 + wB1 + mB1) + csmB1);
    __half2* part = (__half2*)(ws + NB*(imgB1 + wB1 + mB1) + csmB1 + T1B);

    pack_common_kernel<<<NB*NR, 256, 0, stream>>>(0, x_re, x_im, wm_re, wm_im,
                                                  mask, img_t, w_t, m_t);
    for (int b = 0; b < NB; ++b){
      c32* img_b = img_t + (size_t)b*NPOL*PL;
      c32* w_b   = w_t   + (size_t)b*NPOL*NSEG*PL;
      float* m_b = m_t   + (size_t)b*NPOL*NSEG*PL;
      pack_csm_kernel<<<NR, 256, 0, stream>>>(b, 0, NCOIL, csm_re, csm_im, c_t);
      stageA_kernel<<<NCOIL*NPOL*NSEG*16, 256, 0, stream>>>(img_b, w_b, c_t, T1);
      stageB_kernel<<<NCOIL*NPOL*64, 256, 0, stream>>>(T1, m_b);
      stageC_part_kernel<<<NCC*NPOL*16, 256, 0, stream>>>(T1, w_b, c_t, part);
      reduceC_kernel<<<NR, 256, 0, stream>>>(b, part, out);
    }
  } else {
    // ---- fallback: per-batch packing, coil-chunked, atomic stageC ----
    const size_t common = imgB1 + wB1 + mB1;
    int CH = 32;
    while (CH > 2){
      size_t need = common + (size_t)CH*(PL*sizeof(c32) + (size_t)NPOL*NSEG*PL*4);
      if (need <= ws_size) break;
      CH >>= 1;
    }
    c32* img_t = (c32*)ws;
    c32* w_t   = (c32*)(ws + imgB1);
    float* m_t = (float*)(ws + imgB1 + wB1);
    c32* c_t   = (c32*)(ws + common);
    __half2* T1 = (__half2*)(ws + common + (size_t)CH*PL*sizeof(c32));

    for (int b = 0; b < NB; ++b){
      pack_common_kernel<<<NR, 256, 0, stream>>>(b, x_re, x_im, wm_re, wm_im,
                                                 mask, img_t, w_t, m_t);
      for (int c0 = 0; c0 < NCOIL; c0 += CH){
        pack_csm_kernel<<<NR, 256, 0, stream>>>(b, c0, CH, csm_re, csm_im, c_t);
        stageA_kernel<<<CH*NPOL*NSEG*16, 256, 0, stream>>>(img_t, w_t, c_t, T1);
        stageB_kernel<<<CH*NPOL*64, 256, 0, stream>>>(T1, m_t);
        stageC_atomic_kernel<<<(CH/2)*NPOL*16, 256, 0, stream>>>(b, T1, w_t, c_t, out);
      }
    }
  }
}